// Round 2
// baseline (388.137 us; speedup 1.0000x reference)
//
#include <hip/hip_runtime.h>
#include <math.h>

#define B_ 2
#define C_ 32
#define D_ 64
#define H_ 128
#define W_ 128
#define N_ (D_*H_*W_)          // 1048576 = 2^20
#define NW_ (N_/64)            // 16384 words per image
#define P_CAP 2048
#define NEG_CAP 12288
#define PAD 5
#define EPS_ 1e-8f
#define SLICES 64
#define TA 4                   // anchors per thread

// ---------------- pack fg bits + W-dilation + H-dilation (one slab per block) ----
// block = (b,d) slab of H*W = 16384 voxels = 256 bit-words; 1024 threads.
__global__ __launch_bounds__(1024) void k_pack(const int* __restrict__ labels,
                                               unsigned long long* __restrict__ fgbits,
                                               unsigned long long* __restrict__ dilh,
                                               int* cnt_pos, int* cnt_neg, int* done,
                                               float* __restrict__ posum /* +negsum contiguous */) {
    const int bd = blockIdx.x;            // b*D_ + d
    const int tid = threadIdx.x;
    if (bd == 0) {
        if (tid < B_) { cnt_pos[tid] = 0; cnt_neg[tid] = 0; }
        if (tid == 0) done[0] = 0;
    }
    if (bd < 8) {                         // zero posum+negsum: 2*B_*P_CAP = 8192 floats
        posum[bd * 1024 + tid] = 0.f;
    }

    __shared__ unsigned long long fg_s[256];
    __shared__ unsigned long long wd_s[256];
    const int lane = tid & 63;
    const int wv = tid >> 6;              // wave 0..15
    const size_t slab = (size_t)bd * (H_ * W_);
#pragma unroll
    for (int it = 0; it < 16; ++it) {
        unsigned long long m = __ballot(labels[slab + it * 1024 + tid] > 0);
        if (lane == 0) fg_s[it * 16 + wv] = m;
    }
    __syncthreads();

    if (tid < 256) {
        // W-axis dilation (128-bit row = word pair 2h, 2h+1)
        unsigned long long self = fg_s[tid];
        unsigned long long other = fg_s[tid ^ 1];
        unsigned long long o = self;
        if ((tid & 1) == 0) {             // low word
#pragma unroll
            for (int k = 1; k <= PAD; ++k)
                o |= (self >> k) | (self << k) | (other << (64 - k));
        } else {                          // high word
#pragma unroll
            for (int k = 1; k <= PAD; ++k)
                o |= (self << k) | (self >> k) | (other >> (64 - k));
        }
        wd_s[tid] = o;
        fgbits[(size_t)bd * 256 + tid] = self;
    }
    __syncthreads();
    if (tid < 256) {
        // H-axis dilation from LDS
        const int h = tid >> 1;
        const int lo = (h >= PAD) ? -PAD : -h;
        const int hi = (h + PAD <= H_ - 1) ? PAD : (H_ - 1 - h);
        unsigned long long v = 0;
        for (int o = lo; o <= hi; ++o) v |= wd_s[tid + o * 2];
        dilh[(size_t)bd * 256 + tid] = v;
    }
}

// ---------------- fused D-dilation + compact + gather + normalize ----------------
__global__ __launch_bounds__(256) void k_cg(const float* __restrict__ features,
                                            const unsigned long long* __restrict__ fgbits,
                                            const unsigned long long* __restrict__ dilh,
                                            int* cnt_pos, int* cnt_neg,
                                            float* __restrict__ pos_feat,
                                            float* __restrict__ neg_feat) {
    const int g = blockIdx.x * 256 + threadIdx.x;
    const int lane = threadIdx.x & 63;
    const int word = g >> 6;
    const int b = g >> 20;
    const int n = g & (N_ - 1);

    // D-axis dilation fused here: OR of up to 11 wave-uniform 8B loads.
    const int qq = word & (NW_ - 1);
    const int d = qq >> 8;                               // qq / (H_*2)
    const int lo = (d >= PAD) ? -PAD : -d;
    const int hi = (d + PAD <= D_ - 1) ? PAD : (D_ - 1 - d);
    unsigned long long dw = 0;
    for (int o = lo; o <= hi; ++o) dw |= dilh[word + o * (H_ * 2)];

    unsigned long long fgw = fgbits[word];               // wave-uniform load
    unsigned long long rimw = dw & ~fgw;
    if ((fgw | rimw) == 0) return;

    int basep = 0, basen = 0;
    if (lane == 0) {
        if (fgw)  basep = atomicAdd(&cnt_pos[b], __popcll(fgw));
        if (rimw) basen = atomicAdd(&cnt_neg[b], __popcll(rimw));
    }
    basep = __shfl(basep, 0);
    basen = __shfl(basen, 0);

    const unsigned long long ltmask = (lane == 0) ? 0ull : (~0ull >> (64 - lane));
    const bool is_fg = (fgw >> lane) & 1;
    const bool is_rim = (rimw >> lane) & 1;
    if (!is_fg && !is_rim) return;

    int slot; float* dst;
    if (is_fg) {
        slot = basep + __popcll(fgw & ltmask);
        if (slot >= P_CAP) return;
        dst = pos_feat + ((size_t)b * P_CAP + slot) * C_;
    } else {
        slot = basen + __popcll(rimw & ltmask);
        if (slot >= NEG_CAP) return;
        dst = neg_feat + ((size_t)b * NEG_CAP + slot) * C_;
    }

    const float* fbase = features + (size_t)b * C_ * N_ + n;
    float v[C_];
    float ss = 0.f;
#pragma unroll
    for (int c = 0; c < C_; ++c) {
        float x = fbase[(size_t)c * N_];
        v[c] = x;
        ss += x * x;
    }
    float inv = 1.0f / fmaxf(sqrtf(ss), 1e-12f);
#pragma unroll
    for (int c = 0; c < C_; ++c) dst[c] = v[c] * inv;
}

// ---------------- partner-sliced loss + atomic accumulate + fused finalize ------
__device__ __forceinline__ void dot4x(const float4* __restrict__ row4,
                                      const float A[TA][C_], float d[TA]) {
    d[0] = d[1] = d[2] = d[3] = 0.f;
#pragma unroll
    for (int q = 0; q < 8; ++q) {
        float4 v = row4[q];
#pragma unroll
        for (int i = 0; i < TA; ++i) {
            d[i] = fmaf(v.x, A[i][4*q+0], d[i]);
            d[i] = fmaf(v.y, A[i][4*q+1], d[i]);
            d[i] = fmaf(v.z, A[i][4*q+2], d[i]);
            d[i] = fmaf(v.w, A[i][4*q+3], d[i]);
        }
    }
}

__global__ __launch_bounds__(256, 3) void k_loss2(const float* __restrict__ pos_feat,
                                                  const float* __restrict__ neg_feat,
                                                  const int* __restrict__ cnt_pos,
                                                  const int* __restrict__ cnt_neg,
                                                  float* __restrict__ posum,
                                                  float* __restrict__ negsum,
                                                  int* __restrict__ done,
                                                  float* __restrict__ out) {
    const int slice = blockIdx.x;
    const int tile  = blockIdx.y;
    const int b     = blockIdx.z;
    const int np = min(cnt_pos[b], P_CAP);
    const int nn = min(cnt_neg[b], NEG_CAP);
    const int abase = tile * 256;
    const int tid = threadIdx.x;
    const int lane = tid & 63;
    const int w = __builtin_amdgcn_readfirstlane(tid >> 6);

    __shared__ float4 sA4[256 * 8];               // 32 KB
    const bool active = (abase < np);
    if (active) {
        const int total = np + nn;
        // ---- stage the 256-anchor tile through LDS, XOR-swizzled chunks ----
        {
            const float4* src = (const float4*)(pos_feat + ((size_t)b * P_CAP + abase) * C_);
#pragma unroll
            for (int k = 0; k < 8; ++k) {
                const int idx = tid + k * 256;    // linear float4 index (coalesced read)
                const int r = idx >> 3, q = idx & 7;
                sA4[(r << 3) | ((q + r) & 7)] = src[idx];
            }
        }
        __syncthreads();

        // ---- register fill from LDS: thread owns rows r_i = i*64 + lane ----
        float A[TA][C_];
#pragma unroll
        for (int i = 0; i < TA; ++i) {
            const int r = i * 64 + lane;
            const int rbase = r << 3;
            const int rot = r & 7;
#pragma unroll
            for (int q = 0; q < 8; ++q) {
                float4 v = sA4[rbase | ((q + rot) & 7)];
                A[i][4*q+0] = v.x; A[i][4*q+1] = v.y; A[i][4*q+2] = v.z; A[i][4*q+3] = v.w;
            }
        }
        __syncthreads();   // sA4 reused below as reduction scratch

        float ps[TA] = {0.f, 0.f, 0.f, 0.f};
        float ns[TA] = {0.f, 0.f, 0.f, 0.f};

        const int per = (total + SLICES - 1) / SLICES;
        const int r0 = slice * per;
        const int r1 = min(r0 + per, total);
        const int a1 = abase + lane;             // anchor i is a1 + 64*i

        // ---- positive partners in [r0, min(r1,np)) ----
        const int pEnd = min(r1, np);
        const float4* pbase4 = (const float4*)(pos_feat + (size_t)b * P_CAP * C_);
        for (int gr = r0 + w; gr < pEnd; gr += 4) {
            float d[TA];
            dot4x(pbase4 + gr * 8, A, d);
#pragma unroll
            for (int i = 0; i < TA; ++i) {
                float e = __expf(fmaf(d[i], 10.f, -10.f));
                ps[i] += (gr == a1 + 64 * i) ? 0.f : e;
            }
        }
        // ---- negative partners in [max(r0,np), r1) ----
        const int s0 = max(r0, np);
        const float4* nbase4 = (const float4*)(neg_feat + (size_t)b * NEG_CAP * C_);
        for (int gr = s0 + w; gr < r1; gr += 4) {
            float d[TA];
            dot4x(nbase4 + (gr - np) * 8, A, d);
#pragma unroll
            for (int i = 0; i < TA; ++i)
                ns[i] += __expf(fmaf(d[i], 10.f, -10.f));
        }

        // ---- cross-wave reduction (reuse sA4 as scratch: [4][256] x 2) ----
        float* redP = (float*)sA4;           // [4][256]
        float* redN = (float*)sA4 + 4 * 256; // [4][256]
#pragma unroll
        for (int i = 0; i < TA; ++i) {
            redP[w * 256 + i * 64 + lane] = ps[i];
            redN[w * 256 + i * 64 + lane] = ns[i];
        }
        __syncthreads();
        {
            const int a = abase + tid;
            if (a < np) {
                float p = redP[0*256 + tid] + redP[1*256 + tid] + redP[2*256 + tid] + redP[3*256 + tid];
                float n = redN[0*256 + tid] + redN[1*256 + tid] + redN[2*256 + tid] + redN[3*256 + tid];
                atomicAdd(&posum[(size_t)b * P_CAP + a], p);
                atomicAdd(&negsum[(size_t)b * P_CAP + a], n);
            }
        }
    }

    // ---- done-counter: last of ALL blocks finalizes ----
    __shared__ int s_last;
    __syncthreads();
    if (tid == 0) {
        __threadfence();                               // release our atomics
        int prev = atomicAdd(done, 1);
        s_last = (prev == (int)(gridDim.x * gridDim.y * gridDim.z) - 1);
    }
    __syncthreads();
    if (!s_last) return;
    __threadfence();                                   // acquire

    float* sl = (float*)sA4;          // reuse LDS
    float* sc = (float*)sA4 + 256;
    float tot = 0.f, nv = 0.f;
    bool any = false;
    for (int bb = 0; bb < B_; ++bb) {
        const int npb = min(cnt_pos[bb], P_CAP);
        float l = 0.f, c = 0.f;
        for (int a = tid; a < npb; a += 256) {
            float num = atomicAdd(&posum[(size_t)bb * P_CAP + a], 0.f);  // device-scope read
            float den = atomicAdd(&negsum[(size_t)bb * P_CAP + a], 0.f);
            if (num > 0.f) {
                den += num;
                num += EPS_; den += EPS_;
                l += __logf(den) - __logf(num);
                c += 1.f;
            }
        }
        sl[tid] = l; sc[tid] = c;
        __syncthreads();
        for (int off = 128; off > 0; off >>= 1) {
            if (tid < off) { sl[tid] += sl[tid + off]; sc[tid] += sc[tid + off]; }
            __syncthreads();
        }
        if (tid == 0) {
            float ac = sc[0];
            bool valid = (cnt_pos[bb] >= 2) && (cnt_neg[bb] > 0) && (ac > 0.f);
            if (valid) { tot += sl[0] / fmaxf(ac, 1.f); nv += 1.f; any = true; }
        }
        __syncthreads();   // protect sl/sc before next bb iteration
    }
    if (tid == 0) out[0] = any ? tot / fmaxf(nv, 1.f) : 0.f;
}

extern "C" void kernel_launch(void* const* d_in, const int* in_sizes, int n_in,
                              void* d_out, int out_size, void* d_ws, size_t ws_size,
                              hipStream_t stream) {
    const float* features = (const float*)d_in[0];
    const int* labels = (const int*)d_in[1];
    float* out = (float*)d_out;

    // ---- workspace carve ----
    char* p = (char*)d_ws;
    float* pos_feat = (float*)p;                 p += (size_t)B_ * P_CAP * C_ * 4;
    float* neg_feat = (float*)p;                 p += (size_t)B_ * NEG_CAP * C_ * 4;
    float* posum = (float*)p;                    p += (size_t)B_ * P_CAP * 4;   // contiguous with negsum
    float* negsum = (float*)p;                   p += (size_t)B_ * P_CAP * 4;
    unsigned long long* fgbits = (unsigned long long*)p;  p += (size_t)B_ * NW_ * 8;
    unsigned long long* dilh = (unsigned long long*)p;    p += (size_t)B_ * NW_ * 8;
    int* cnt_pos = (int*)p;                      p += B_ * 4;
    int* cnt_neg = (int*)p;                      p += B_ * 4;
    int* done = (int*)p;                         p += 4;

    const int threads = 256;
    const int vox_blocks = B_ * N_ / threads;          // 8192

    k_pack<<<B_ * D_, 1024, 0, stream>>>(labels, fgbits, dilh,
                                         cnt_pos, cnt_neg, done, posum);
    k_cg<<<vox_blocks, threads, 0, stream>>>(features, fgbits, dilh,
                                             cnt_pos, cnt_neg, pos_feat, neg_feat);
    dim3 lgrid(SLICES, P_CAP / 256, B_);
    k_loss2<<<lgrid, 256, 0, stream>>>(pos_feat, neg_feat, cnt_pos, cnt_neg,
                                       posum, negsum, done, out);
}